// Round 2
// baseline (2580.596 us; speedup 1.0000x reference)
//
#include <hip/hip_runtime.h>
#include <cstdint>
#include <cstddef>

// ---------------------------------------------------------------------------
// AttentionVAE fused forward, f32. One block = 32 rows, 256 threads.
// RNG: JAX threefry2x32 in *partitionable* mode (jax >= 0.4.36 default):
//   split:  ek[j] = threefry(key, (0, j))            (both output words)
//   bits_i: o0 ^ o1 of threefry(ek, (0, i))          (i = flat element index)
// ---------------------------------------------------------------------------

#define NROWS 32

static constexpr size_t OFF_RECON = 0;
static constexpr size_t OFF_MEAN  = (size_t)262144 * 196;              // 51380224
static constexpr size_t OFF_LOGV  = OFF_MEAN + (size_t)262144 * 8;     // 53477376
static constexpr size_t OFF_ATTN  = OFF_LOGV + (size_t)262144 * 8;     // 55574528
static constexpr size_t OFF_LOSS  = OFF_ATTN + (size_t)262144 * 196;   // 106954752

struct Params {
  const float* x;
  const float* fa_w1; const float* fa_b1; const float* fa_w2; const float* fa_b2;
  const float* e_w1;  const float* e_b1;  const float* e_w2;  const float* e_b2;
  const float* e_w3;  const float* e_b3;  const float* e_wm;  const float* e_bm;
  const float* e_wv;  const float* e_bv;
  const float* d_w1;  const float* d_b1;  const float* d_w2;  const float* d_b2;
  const float* d_w3;  const float* d_b3;  const float* d_w4;  const float* d_b4;
  const float* la_w;  const float* la_b;
  float* out;
  uint32_t key[8]; // ek0(k0,k1), ek1, ek2, ek3
};

// --------------------------- Threefry-2x32 (JAX) ---------------------------
__host__ __device__ inline void tf2x32(uint32_t k0, uint32_t k1, uint32_t x0, uint32_t x1,
                                       uint32_t& o0, uint32_t& o1)
{
  uint32_t kx = k0 ^ k1 ^ 0x1BD11BDAu;
  uint32_t a = x0 + k0, b = x1 + k1;
#define TF_R(r) { a += b; b = (b << (r)) | (b >> (32 - (r))); b ^= a; }
  TF_R(13) TF_R(15) TF_R(26) TF_R(6)
  a += k1; b += kx + 1u;
  TF_R(17) TF_R(29) TF_R(16) TF_R(24)
  a += kx; b += k0 + 2u;
  TF_R(13) TF_R(15) TF_R(26) TF_R(6)
  a += k0; b += k1 + 3u;
  TF_R(17) TF_R(29) TF_R(16) TF_R(24)
  a += k1; b += kx + 4u;
  TF_R(13) TF_R(15) TF_R(26) TF_R(6)
  a += kx; b += k0 + 5u;
#undef TF_R
  o0 = a; o1 = b;
}

// jax.random.normal element i (partitionable mode): bits = o0^o1 of
// threefry(key, (0, i)); uniform in [nextafter(-1,0), 1); sqrt(2)*erfinv.
__device__ __forceinline__ float jax_normal(uint32_t k0, uint32_t k1, uint32_t idx)
{
  uint32_t o0, o1;
  tf2x32(k0, k1, 0u, idx, o0, o1);
  uint32_t bits = o0 ^ o1;
  float f = __uint_as_float((bits >> 9) | 0x3f800000u) - 1.0f;
  const float lo = -0.99999994f;
  float u = fmaf(f, 2.0f, lo);   // (hi - lo) rounds to 2.0f; f*2 exact
  u = fmaxf(u, lo);
  // XLA ErfInv32 (Giles)
  float w = -log1pf(-u * u);
  float p;
  if (w < 5.0f) {
    w -= 2.5f;
    p = 2.81022636e-08f;
    p = fmaf(p, w, 3.43273939e-07f);
    p = fmaf(p, w, -3.5233877e-06f);
    p = fmaf(p, w, -4.39150654e-06f);
    p = fmaf(p, w, 0.00021858087f);
    p = fmaf(p, w, -0.00125372503f);
    p = fmaf(p, w, -0.00417768164f);
    p = fmaf(p, w, 0.246640727f);
    p = fmaf(p, w, 1.50140941f);
  } else {
    w = sqrtf(w) - 3.0f;
    p = -0.000200214257f;
    p = fmaf(p, w, 0.000100950558f);
    p = fmaf(p, w, 0.00134934322f);
    p = fmaf(p, w, -0.00367342844f);
    p = fmaf(p, w, 0.00573950773f);
    p = fmaf(p, w, -0.0076224613f);
    p = fmaf(p, w, 0.00943887047f);
    p = fmaf(p, w, 1.00167406f);
    p = fmaf(p, w, 2.83297682f);
  }
  return 1.41421356237f * (p * u);
}

// ------------------------------ GEMM helpers -------------------------------
template<int K, int N, int LDW>
__device__ __forceinline__ void gemm_acc(const float* __restrict__ W,
                                         const float* __restrict__ bias,
                                         const float* sIn, int ldin,
                                         int rg, int c,
                                         float (&acc)[4][(N + 31) / 32])
{
  constexpr int NJ = (N + 31) / 32;
#pragma unroll
  for (int j = 0; j < NJ; ++j) {
    int n = c + 32 * j;
    float bv = (n < N) ? bias[n] : 0.f;
#pragma unroll
    for (int rr = 0; rr < 4; ++rr) acc[rr][j] = bv;
  }
  const float* in0 = sIn + (rg * 4) * ldin;
  const float* wp = W + c;
  for (int k = 0; k < K; ++k) {
    float w[NJ];
#pragma unroll
    for (int j = 0; j < NJ; ++j) {
      int n = c + 32 * j;
      w[j] = (n < N) ? wp[32 * j] : 0.f;
    }
#pragma unroll
    for (int rr = 0; rr < 4; ++rr) {
      float iv = in0[rr * ldin + k];
#pragma unroll
      for (int j = 0; j < NJ; ++j) acc[rr][j] = fmaf(iv, w[j], acc[rr][j]);
    }
    wp += LDW;
  }
}

// act: 0 = tanh, 1 = leaky_relu(0.1)
template<int N, int LD>
__device__ __forceinline__ void store_act(float* O, float (&acc)[4][(N + 31) / 32],
                                          int rg, int c, int act)
{
  constexpr int NJ = (N + 31) / 32;
#pragma unroll
  for (int rr = 0; rr < 4; ++rr) {
    int r = rg * 4 + rr;
#pragma unroll
    for (int j = 0; j < NJ; ++j) {
      int n = c + 32 * j;
      if (n < N) {
        float v = acc[rr][j];
        v = (act == 0) ? tanhf(v) : (v > 0.f ? v : 0.1f * v);
        O[r * LD + n] = v;
      }
    }
  }
}

__device__ __forceinline__ float sigmoidf_(float x) { return 1.0f / (1.0f + expf(-x)); }

// Decoder hidden stack: z[32][9] -> DEC1[32][33] -> DEC2[32][65] -> DEC3[32][97]
__device__ __forceinline__ void dec_hidden(const Params& p, const float* sZ,
                                           float* DEC1, float* DEC2, float* DEC3,
                                           int rg, int c)
{
  {
    float acc[4][1];
    gemm_acc<8, 32, 32>(p.d_w1, p.d_b1, sZ, 9, rg, c, acc);
    store_act<32, 33>(DEC1, acc, rg, c, 1);
  }
  __syncthreads();
  {
    float acc[4][2];
    gemm_acc<32, 64, 64>(p.d_w2, p.d_b2, DEC1, 33, rg, c, acc);
    store_act<64, 65>(DEC2, acc, rg, c, 1);
  }
  __syncthreads();
  {
    float acc[4][3];
    gemm_acc<64, 96, 96>(p.d_w3, p.d_b3, DEC2, 65, rg, c, acc);
    store_act<96, 97>(DEC3, acc, rg, c, 1);
  }
  __syncthreads();
}

template<int DIM>
__device__ __forceinline__ void loss_tail(const Params& p, const float* DEC3,
                                          const float* H, int ldh, float* sLL,
                                          int li, int rg, int c)
{
  constexpr int NJ = (DIM + 31) / 32;
  float acc[4][NJ];
  gemm_acc<96, DIM, 196>(p.d_w4, p.d_b4, DEC3, 97, rg, c, acc);
#pragma unroll
  for (int rr = 0; rr < 4; ++rr) {
    float s = 0.f;
#pragma unroll
    for (int j = 0; j < NJ; ++j) {
      int n = c + 32 * j;
      if (n < DIM) {
        float lr = sigmoidf_(acc[rr][j]);
        float d = H[(rg * 4 + rr) * ldh + n] - lr;
        s = fmaf(d, d, s);
      }
    }
#pragma unroll
    for (int m = 16; m >= 1; m >>= 1) s += __shfl_xor(s, m, 64);
    if (c == 0) sLL[(rg * 4 + rr) * 3 + li] = s * (1.0f / DIM);
  }
}

// ------------------------------- the kernel --------------------------------
__launch_bounds__(256, 2)
__global__ void vae_fused(Params p)
{
  // LDS (floats): R1 6304 | R2 3168 | R3 6304 | MEAN 288 | STD 288 | Z 288 | LL 96
  __shared__ float sm[16736];
  float* R1 = sm;
  float* R2 = sm + 6304;
  float* R3 = sm + 9472;
  float* sMEAN = sm + 15776;
  float* sSTD  = sm + 16064;
  float* sZ    = sm + 16352;
  float* sLL   = sm + 16640;

  float* XA  = R1;          // [32][197] x, then x_attn
  float* T   = R2;          // [32][99]  fa hidden
  float* H1  = R2;          // [32][97]  (aliases T after FA done)
  float* H2  = R1;          // [32][65]  (aliases XA after E1)
  float* H3  = R1 + 2080;   // [32][33]
  float* DEC1 = R3;         // [32][33]
  float* DEC2 = R3 + 1056;  // [32][65]
  float* DEC3 = R3 + 3136;  // [32][97]

  const int tid = threadIdx.x;
  const int c  = tid & 31;
  const int rg = tid >> 5;
  const int rb0 = blockIdx.x * NROWS;

  // ---- load x tile ----
#pragma unroll
  for (int rr = 0; rr < 4; ++rr) {
    int r = rg * 4 + rr;
    const float* xr = p.x + (size_t)(rb0 + r) * 196;
#pragma unroll
    for (int j = 0; j < 7; ++j) {
      int n = c + 32 * j;
      if (n < 196) XA[r * 197 + n] = xr[n];
    }
  }
  __syncthreads();

  // ---- FA1: T = tanh(x @ fa_w1 + b) ----
  {
    float acc[4][4];
    gemm_acc<196, 98, 98>(p.fa_w1, p.fa_b1, XA, 197, rg, c, acc);
    store_act<98, 99>(T, acc, rg, c, 0);
  }
  __syncthreads();

  // ---- FA2 + attention normalize + x_attn (in-register epilogue) ----
  {
    float acc[4][7];
    gemm_acc<98, 196, 196>(p.fa_w2, p.fa_b2, T, 99, rg, c, acc);
#pragma unroll
    for (int rr = 0; rr < 4; ++rr) {
      float s = 0.f;
#pragma unroll
      for (int j = 0; j < 7; ++j) {
        int n = c + 32 * j;
        if (n < 196) {
          acc[rr][j] = sigmoidf_(acc[rr][j]);
          s += acc[rr][j];
        }
      }
#pragma unroll
      for (int m = 16; m >= 1; m >>= 1) s += __shfl_xor(s, m, 64);
      float inv = 1.0f / (s * (1.0f / 196.0f) + 1e-8f);
      int r = rg * 4 + rr;
      float* oa = p.out + OFF_ATTN + (size_t)(rb0 + r) * 196;
#pragma unroll
      for (int j = 0; j < 7; ++j) {
        int n = c + 32 * j;
        if (n < 196) {
          float aw = acc[rr][j] * inv;
          oa[n] = aw;
          XA[r * 197 + n] *= aw;   // x_attn in place
        }
      }
    }
  }
  __syncthreads();

  // ---- encoder ----
  {
    float acc[4][3];
    gemm_acc<196, 96, 96>(p.e_w1, p.e_b1, XA, 197, rg, c, acc);
    store_act<96, 97>(H1, acc, rg, c, 1);   // overwrites T (dead)
  }
  __syncthreads();
  {
    float acc[4][2];
    gemm_acc<96, 64, 64>(p.e_w2, p.e_b2, H1, 97, rg, c, acc);
    store_act<64, 65>(H2, acc, rg, c, 1);   // overwrites XA (dead)
  }
  __syncthreads();
  {
    float acc[4][1];
    gemm_acc<64, 32, 32>(p.e_w3, p.e_b3, H2, 65, rg, c, acc);
    store_act<32, 33>(H3, acc, rg, c, 1);
  }
  __syncthreads();

  // ---- mean / log_var / std ----
  if (c < 16) {
    int which = c >> 3;
    int n = c & 7;
    const float* W  = which ? p.e_wv : p.e_wm;
    const float* bb = which ? p.e_bv : p.e_bm;
    float a0 = bb[n], a1 = bb[n], a2 = bb[n], a3 = bb[n];
    for (int k = 0; k < 32; ++k) {
      float w = W[k * 8 + n];
      a0 = fmaf(H3[(rg * 4 + 0) * 33 + k], w, a0);
      a1 = fmaf(H3[(rg * 4 + 1) * 33 + k], w, a1);
      a2 = fmaf(H3[(rg * 4 + 2) * 33 + k], w, a2);
      a3 = fmaf(H3[(rg * 4 + 3) * 33 + k], w, a3);
    }
    float av[4] = {a0, a1, a2, a3};
#pragma unroll
    for (int rr = 0; rr < 4; ++rr) {
      int r = rg * 4 + rr;
      size_t gr = (size_t)(rb0 + r) * 8 + n;
      if (which == 0) {
        sMEAN[r * 9 + n] = av[rr];
        p.out[OFF_MEAN + gr] = av[rr];
      } else {
        p.out[OFF_LOGV + gr] = av[rr];
        sSTD[r * 9 + n] = expf(0.5f * av[rr]);
      }
    }
  }
  __syncthreads();

  // ---- draw 0: recon ----
  {
    int r = tid >> 3, jj = tid & 7;
    uint32_t idx = (uint32_t)(rb0 + r) * 8u + (uint32_t)jj;
    float eps = jax_normal(p.key[0], p.key[1], idx);
    sZ[r * 9 + jj] = fmaf(eps, sSTD[r * 9 + jj], sMEAN[r * 9 + jj]);
  }
  __syncthreads();
  dec_hidden(p, sZ, DEC1, DEC2, DEC3, rg, c);
  {
    float acc[4][7];
    gemm_acc<96, 196, 196>(p.d_w4, p.d_b4, DEC3, 97, rg, c, acc);
#pragma unroll
    for (int rr = 0; rr < 4; ++rr) {
      int r = rg * 4 + rr;
      float* orc = p.out + OFF_RECON + (size_t)(rb0 + r) * 196;
#pragma unroll
      for (int j = 0; j < 7; ++j) {
        int n = c + 32 * j;
        if (n < 196) orc[n] = sigmoidf_(acc[rr][j]);
      }
    }
  }

  // ---- draws 1..3: layer losses ----
  {
    int r = tid >> 3, jj = tid & 7;
    uint32_t idx = (uint32_t)(rb0 + r) * 8u + (uint32_t)jj;
    float eps = jax_normal(p.key[2], p.key[3], idx);
    sZ[r * 9 + jj] = fmaf(eps, sSTD[r * 9 + jj], sMEAN[r * 9 + jj]);
  }
  __syncthreads();
  dec_hidden(p, sZ, DEC1, DEC2, DEC3, rg, c);
  loss_tail<96>(p, DEC3, H1, 97, sLL, 0, rg, c);

  {
    int r = tid >> 3, jj = tid & 7;
    uint32_t idx = (uint32_t)(rb0 + r) * 8u + (uint32_t)jj;
    float eps = jax_normal(p.key[4], p.key[5], idx);
    sZ[r * 9 + jj] = fmaf(eps, sSTD[r * 9 + jj], sMEAN[r * 9 + jj]);
  }
  __syncthreads();
  dec_hidden(p, sZ, DEC1, DEC2, DEC3, rg, c);
  loss_tail<64>(p, DEC3, H2, 65, sLL, 1, rg, c);

  {
    int r = tid >> 3, jj = tid & 7;
    uint32_t idx = (uint32_t)(rb0 + r) * 8u + (uint32_t)jj;
    float eps = jax_normal(p.key[6], p.key[7], idx);
    sZ[r * 9 + jj] = fmaf(eps, sSTD[r * 9 + jj], sMEAN[r * 9 + jj]);
  }
  __syncthreads();
  dec_hidden(p, sZ, DEC1, DEC2, DEC3, rg, c);
  loss_tail<32>(p, DEC3, H3, 33, sLL, 2, rg, c);

  __syncthreads();

  // ---- layer attention + weighted loss ----
  if (tid < 32) {
    int r = tid;
    float l0 = sLL[r * 3 + 0], l1 = sLL[r * 3 + 1], l2 = sLL[r * 3 + 2];
    float lg[3];
#pragma unroll
    for (int i = 0; i < 3; ++i)
      lg[i] = p.la_b[i] + l0 * p.la_w[0 * 3 + i] + l1 * p.la_w[1 * 3 + i] + l2 * p.la_w[2 * 3 + i];
    float mx = fmaxf(lg[0], fmaxf(lg[1], lg[2]));
    float e0 = expf(lg[0] - mx), e1 = expf(lg[1] - mx), e2 = expf(lg[2] - mx);
    float inv = 1.0f / (e0 + e1 + e2);
    float wll = (l0 * e0 + l1 * e1 + l2 * e2) * inv;
#pragma unroll
    for (int m = 16; m >= 1; m >>= 1) wll += __shfl_xor(wll, m, 64);
    if (tid == 0) atomicAdd(p.out + OFF_LOSS, wll * (1.0f / 262144.0f));
  }
}

// ------------------------------ host launcher ------------------------------
extern "C" void kernel_launch(void* const* d_in, const int* in_sizes, int n_in,
                              void* d_out, int out_size, void* d_ws, size_t ws_size,
                              hipStream_t stream)
{
  (void)in_sizes; (void)n_in; (void)d_ws; (void)ws_size; (void)out_size;
  Params p;
  p.x     = (const float*)d_in[0];
  p.fa_w1 = (const float*)d_in[1];  p.fa_b1 = (const float*)d_in[2];
  p.fa_w2 = (const float*)d_in[3];  p.fa_b2 = (const float*)d_in[4];
  p.e_w1  = (const float*)d_in[5];  p.e_b1  = (const float*)d_in[6];
  p.e_w2  = (const float*)d_in[7];  p.e_b2  = (const float*)d_in[8];
  p.e_w3  = (const float*)d_in[9];  p.e_b3  = (const float*)d_in[10];
  p.e_wm  = (const float*)d_in[11]; p.e_bm  = (const float*)d_in[12];
  p.e_wv  = (const float*)d_in[13]; p.e_bv  = (const float*)d_in[14];
  p.d_w1  = (const float*)d_in[15]; p.d_b1  = (const float*)d_in[16];
  p.d_w2  = (const float*)d_in[17]; p.d_b2  = (const float*)d_in[18];
  p.d_w3  = (const float*)d_in[19]; p.d_b3  = (const float*)d_in[20];
  p.d_w4  = (const float*)d_in[21]; p.d_b4  = (const float*)d_in[22];
  p.la_w  = (const float*)d_in[23]; p.la_b  = (const float*)d_in[24];
  p.out   = (float*)d_out;

  // jax.random.split(jax.random.key(42), 4), partitionable/foldlike mode:
  // ek[j] = threefry2x32((0,42), (0, j)) -> (o0, o1) is the key pair.
  for (uint32_t j = 0; j < 4; ++j) {
    uint32_t o0, o1;
    tf2x32(0u, 42u, 0u, j, o0, o1);
    p.key[2 * j] = o0; p.key[2 * j + 1] = o1;
  }

  // zero the loss accumulator (graph-capture-safe async memset)
  hipMemsetAsync((char*)d_out + OFF_LOSS * sizeof(float), 0, sizeof(float), stream);

  vae_fused<<<262144 / NROWS, 256, 0, stream>>>(p);
}

// Round 3
// 420.520 us; speedup vs baseline: 6.1367x; 6.1367x over previous
//
#include <hip/hip_runtime.h>
#include <cstdint>
#include <cstddef>

// ---------------------------------------------------------------------------
// AttentionVAE fused forward — bf16 MFMA version.
// One block = 32 rows (2 MFMA m-tiles), 256 threads = 4 waves.
// Weights are pre-packed to mfma_f32_16x16x32_bf16 B-fragment order in d_ws
// by pack_w. Activations live in LDS as bf16 (padded, odd-16B strides).
// ---------------------------------------------------------------------------

typedef short short8 __attribute__((ext_vector_type(8)));
typedef float f32x4  __attribute__((ext_vector_type(4)));
typedef unsigned short u16x4 __attribute__((ext_vector_type(4)));

static constexpr size_t OFF_RECON = 0;
static constexpr size_t OFF_MEAN  = (size_t)262144 * 196;
static constexpr size_t OFF_LOGV  = OFF_MEAN + (size_t)262144 * 8;
static constexpr size_t OFF_ATTN  = OFF_LOGV + (size_t)262144 * 8;
static constexpr size_t OFF_LOSS  = OFF_ATTN + (size_t)262144 * 196;

// ws fragment offsets (bf16 elements). elems = Kt*Nt*512 per layer.
static constexpr int WS_FA1 = 0;       // K196 N98  Kt7 Nt7
static constexpr int WS_FA2 = 25088;   // K98  N196 Kt4 Nt13
static constexpr int WS_E1  = 51712;   // K196 N96  Kt7 Nt6
static constexpr int WS_E2  = 73216;   // K96  N64  Kt3 Nt4
static constexpr int WS_E3  = 79360;   // K64  N32  Kt2 Nt2
static constexpr int WS_EMV = 81408;   // K32  N16  Kt1 Nt1 (mean|logvar)
static constexpr int WS_D1  = 81920;   // K8   N32  Kt1 Nt2
static constexpr int WS_D2  = 82944;   // K32  N64  Kt1 Nt4
static constexpr int WS_D3  = 84992;   // K64  N96  Kt2 Nt6
static constexpr int WS_D4  = 91136;   // K96  N196 Kt3 Nt13
static constexpr int WS_TOT = 111104;

// LDS layout (ushort units)
static constexpr int XA0 = 0;      // [32][232] x / x_attn   (E1/FA1 K=196<224 read)
static constexpr int T0  = 7424;   // [32][136] fa hidden    (FA2 K=98<128 read)
static constexpr int R30 = 11776;  // TA [32][200] a-vals; later DEC2/DEC3
static constexpr int H1o = T0;     // [32][104]
static constexpr int H2o = 0;      // [32][72]
static constexpr int H3o = 2304;   // [32][40]
static constexpr int ZBo = 3584;   // [32][40]  (D1 K=8<32 read -> pads zeroed)
static constexpr int D1o = 4864;   // [32][40]
static constexpr int D2o = R30;          // [32][72]
static constexpr int D3o = R30 + 2304;   // [32][104]
static constexpr int SU_TOT = 18176;
// sF: MEAN [32][9] @0, STD [32][9] @288, ATT[32] @576, LL[3][32] @608
static constexpr int SF_TOT = 704;

struct Params {
  const float* x;
  const float* fa_w1; const float* fa_b1; const float* fa_w2; const float* fa_b2;
  const float* e_w1;  const float* e_b1;  const float* e_w2;  const float* e_b2;
  const float* e_w3;  const float* e_b3;  const float* e_wm;  const float* e_bm;
  const float* e_wv;  const float* e_bv;
  const float* d_w1;  const float* d_b1;  const float* d_w2;  const float* d_b2;
  const float* d_w3;  const float* d_b3;  const float* d_w4;  const float* d_b4;
  const float* la_w;  const float* la_b;
  float* out;
  uint32_t key[8];
};

// --------------------------- Threefry-2x32 (JAX) ---------------------------
__host__ __device__ inline void tf2x32(uint32_t k0, uint32_t k1, uint32_t x0, uint32_t x1,
                                       uint32_t& o0, uint32_t& o1)
{
  uint32_t kx = k0 ^ k1 ^ 0x1BD11BDAu;
  uint32_t a = x0 + k0, b = x1 + k1;
#define TF_R(r) { a += b; b = (b << (r)) | (b >> (32 - (r))); b ^= a; }
  TF_R(13) TF_R(15) TF_R(26) TF_R(6)
  a += k1; b += kx + 1u;
  TF_R(17) TF_R(29) TF_R(16) TF_R(24)
  a += kx; b += k0 + 2u;
  TF_R(13) TF_R(15) TF_R(26) TF_R(6)
  a += k0; b += k1 + 3u;
  TF_R(17) TF_R(29) TF_R(16) TF_R(24)
  a += k1; b += kx + 4u;
  TF_R(13) TF_R(15) TF_R(26) TF_R(6)
  a += kx; b += k0 + 5u;
#undef TF_R
  o0 = a; o1 = b;
}

__device__ __forceinline__ float jax_normal(uint32_t k0, uint32_t k1, uint32_t idx)
{
  uint32_t o0, o1;
  tf2x32(k0, k1, 0u, idx, o0, o1);
  uint32_t bits = o0 ^ o1;
  float f = __uint_as_float((bits >> 9) | 0x3f800000u) - 1.0f;
  const float lo = -0.99999994f;
  float u = fmaf(f, 2.0f, lo);
  u = fmaxf(u, lo);
  float w = -log1pf(-u * u);
  float p;
  if (w < 5.0f) {
    w -= 2.5f;
    p = 2.81022636e-08f;
    p = fmaf(p, w, 3.43273939e-07f);
    p = fmaf(p, w, -3.5233877e-06f);
    p = fmaf(p, w, -4.39150654e-06f);
    p = fmaf(p, w, 0.00021858087f);
    p = fmaf(p, w, -0.00125372503f);
    p = fmaf(p, w, -0.00417768164f);
    p = fmaf(p, w, 0.246640727f);
    p = fmaf(p, w, 1.50140941f);
  } else {
    w = sqrtf(w) - 3.0f;
    p = -0.000200214257f;
    p = fmaf(p, w, 0.000100950558f);
    p = fmaf(p, w, 0.00134934322f);
    p = fmaf(p, w, -0.00367342844f);
    p = fmaf(p, w, 0.00573950773f);
    p = fmaf(p, w, -0.0076224613f);
    p = fmaf(p, w, 0.00943887047f);
    p = fmaf(p, w, 1.00167406f);
    p = fmaf(p, w, 2.83297682f);
  }
  return 1.41421356237f * (p * u);
}

// ------------------------------ bf16 helpers -------------------------------
__host__ __device__ __forceinline__ unsigned short f2b(float f) {
  uint32_t u = __float_as_uint(f);
  uint32_t r = u + 0x7fffu + ((u >> 16) & 1u);   // RNE (finite inputs)
  return (unsigned short)(r >> 16);
}
__device__ __forceinline__ float b2f(unsigned short h) {
  return __uint_as_float(((uint32_t)h) << 16);
}
__device__ __forceinline__ float sigm(float x) { return 1.0f / (1.0f + __expf(-x)); }

// ------------------------------ weight packer ------------------------------
__global__ void pack_w(Params p, unsigned short* ws)
{
  int e = blockIdx.x * 256 + threadIdx.x;
  if (e >= WS_TOT) return;
  int base, Kt, K, N, special = 0; const float* src = nullptr;
  if (e < WS_FA2)      { base = WS_FA1; Kt = 7; K = 196; N = 98;  src = p.fa_w1; }
  else if (e < WS_E1)  { base = WS_FA2; Kt = 4; K = 98;  N = 196; src = p.fa_w2; }
  else if (e < WS_E2)  { base = WS_E1;  Kt = 7; K = 196; N = 96;  src = p.e_w1; }
  else if (e < WS_E3)  { base = WS_E2;  Kt = 3; K = 96;  N = 64;  src = p.e_w2; }
  else if (e < WS_EMV) { base = WS_E3;  Kt = 2; K = 64;  N = 32;  src = p.e_w3; }
  else if (e < WS_D1)  { base = WS_EMV; Kt = 1; K = 32;  N = 16;  special = 1; }
  else if (e < WS_D2)  { base = WS_D1;  Kt = 1; K = 8;   N = 32;  src = p.d_w1; }
  else if (e < WS_D3)  { base = WS_D2;  Kt = 1; K = 32;  N = 64;  src = p.d_w2; }
  else if (e < WS_D4)  { base = WS_D3;  Kt = 2; K = 64;  N = 96;  src = p.d_w3; }
  else                 { base = WS_D4;  Kt = 3; K = 96;  N = 196; src = p.d_w4; }
  int local = e - base;
  int j = local & 7;
  int lane = (local >> 3) & 63;
  int t = local >> 9;
  int kt = t % Kt, nt = t / Kt;
  int k = kt * 32 + ((lane >> 4) << 3) + j;
  int n = (nt << 4) + (lane & 15);
  float v = 0.f;
  if (k < K && n < N) {
    if (special) v = (n < 8) ? p.e_wm[k * 8 + n] : p.e_wv[k * 8 + (n - 8)];
    else v = src[k * N + n];
  }
  ws[e] = f2b(v);
}

// ------------------------------ MFMA tile ----------------------------------
// A: LDS bf16 [32][sA], lane holds row=lane&15 (+16*mt), k=(lane>>4)*8+j.
// B: pre-packed fragments, lane loads 16B at ((nt*Kt+kt)*64+lane)*8.
template<int Kt>
__device__ __forceinline__ f32x4 tile_acc(const unsigned short* A, int sA,
                                          const unsigned short* B,
                                          int mt, int nt, int lane)
{
  f32x4 acc = {0.f, 0.f, 0.f, 0.f};
  const unsigned short* ar = A + (mt * 16 + (lane & 15)) * sA + ((lane >> 4) << 3);
  const unsigned short* bp = B + ((nt * Kt) * 64 + lane) * 8;
#pragma unroll
  for (int kt = 0; kt < Kt; ++kt) {
    short8 av = *(const short8*)(ar + kt * 32);
    short8 bv = *(const short8*)(bp + kt * 512);
    acc = __builtin_amdgcn_mfma_f32_16x16x32_bf16(av, bv, acc, 0, 0, 0);
  }
  return acc;
}

// generic GEMM + act + bf16 LDS store. act: 0 tanh, 1 lrelu
template<int Kt, int Nt>
__device__ __forceinline__ void layer_act(unsigned short* sU, int aOff, int sA,
                                          int dOff, int sD,
                                          const unsigned short* ws, int wsOff,
                                          const float* bias, int N, int act,
                                          int lane, int wv)
{
  for (int t = wv; t < 2 * Nt; t += 4) {
    int mt = t & 1, nt = t >> 1;
    f32x4 acc = tile_acc<Kt>(sU + aOff, sA, ws + wsOff, mt, nt, lane);
    int col = nt * 16 + (lane & 15);
    float bv = (col < N) ? bias[col] : 0.f;
#pragma unroll
    for (int r = 0; r < 4; ++r) {
      int row = mt * 16 + ((lane >> 4) << 2) + r;
      float v = acc[r] + bv;
      v = (act == 0) ? tanhf(v) : (v > 0.f ? v : 0.1f * v);
      sU[dOff + row * sD + col] = f2b(v);
    }
  }
}

// D4 partial (loss) tail
template<int NtL>
__device__ __forceinline__ void loss_tail(unsigned short* sU, float* sF,
                                          const unsigned short* ws,
                                          const float* d_b4,
                                          int hOff, int sH, float invD, int li,
                                          int lane, int wv)
{
  for (int t = wv; t < 2 * NtL; t += 4) {
    int mt = t & 1, nt = t >> 1;
    f32x4 acc = tile_acc<3>(sU + D3o, 104, ws + WS_D4, mt, nt, lane);
    int col = nt * 16 + (lane & 15);
    float bv = d_b4[col];
#pragma unroll
    for (int r = 0; r < 4; ++r) {
      int row = mt * 16 + ((lane >> 4) << 2) + r;
      float lr = sigm(acc[r] + bv);
      float d = b2f(sU[hOff + row * sH + col]) - lr;
      float s = d * d;
#pragma unroll
      for (int m = 1; m <= 8; m <<= 1) s += __shfl_xor(s, m, 64);
      if ((lane & 15) == 0) atomicAdd(&sF[608 + li * 32 + row], s * invD);
    }
  }
}

// ------------------------------- the kernel --------------------------------
__launch_bounds__(256, 4)
__global__ void vae_fused(Params p, const unsigned short* ws)
{
  __shared__ unsigned short sU[SU_TOT];
  __shared__ float sF[SF_TOT];

  const int tid = threadIdx.x;
  const int lane = tid & 63;
  const int wv = tid >> 6;
  const int rb0 = blockIdx.x * 32;

  // ---- init: zero ATT/LL accumulators; load x (float4 -> bf16); zero pads --
  if (tid < 128) sF[576 + tid] = 0.f;
  for (int idx = tid; idx < 1568; idx += 256) {           // 32 rows * 49 quads
    int row = idx / 49, q = idx - row * 49;
    f32x4 xv = *(const f32x4*)(p.x + (size_t)(rb0 + row) * 196 + 4 * q);
    u16x4 h = { f2b(xv[0]), f2b(xv[1]), f2b(xv[2]), f2b(xv[3]) };
    *(u16x4*)&sU[XA0 + row * 232 + 4 * q] = h;
  }
  { int row = tid >> 3; for (int c = 196 + (tid & 7); c < 232; c += 8) sU[XA0 + row * 232 + c] = 0; }
  __syncthreads();

  // ---- FA1: T = tanh(x @ fa_w1 + b)  [K196 N98] ----
  layer_act<7, 7>(sU, XA0, 232, T0, 136, ws, WS_FA1, p.fa_b1, 98, 0, lane, wv);
  { int row = tid >> 3; for (int c = 112 + (tid & 7); c < 136; c += 8) sU[T0 + row * 136 + c] = 0; }
  __syncthreads();

  // ---- FA2: a = sigmoid(T @ fa_w2 + b) -> TA, row sums -> sATT ----
  for (int t = wv; t < 26; t += 4) {
    int mt = t & 1, nt = t >> 1;
    f32x4 acc = tile_acc<4>(sU + T0, 136, ws + WS_FA2, mt, nt, lane);
    int col = nt * 16 + (lane & 15);
    bool valid = col < 196;
    float bv = valid ? p.fa_b2[col] : 0.f;
#pragma unroll
    for (int r = 0; r < 4; ++r) {
      int row = mt * 16 + ((lane >> 4) << 2) + r;
      float a = sigm(acc[r] + bv);
      if (valid) sU[R30 + row * 200 + col] = f2b(a);
      float s = valid ? a : 0.f;
#pragma unroll
      for (int m = 1; m <= 8; m <<= 1) s += __shfl_xor(s, m, 64);
      if ((lane & 15) == 0) atomicAdd(&sF[576 + row], s);
    }
  }
  __syncthreads();

  // ---- attention apply: attn_out = a*inv, XA *= a*inv ----
  for (int idx = tid; idx < 1568; idx += 256) {
    int row = idx / 49, q = idx - row * 49;
    float inv = 1.0f / (sF[576 + row] * (1.0f / 196.0f) + 1e-8f);
    u16x4 ah = *(const u16x4*)&sU[R30 + row * 200 + 4 * q];
    u16x4 xh = *(const u16x4*)&sU[XA0 + row * 232 + 4 * q];
    f32x4 aw;
    u16x4 xo;
#pragma unroll
    for (int i = 0; i < 4; ++i) {
      aw[i] = b2f(ah[i]) * inv;
      xo[i] = f2b(b2f(xh[i]) * aw[i]);
    }
    __builtin_nontemporal_store(aw, (f32x4*)(p.out + OFF_ATTN + (size_t)(rb0 + row) * 196 + 4 * q));
    *(u16x4*)&sU[XA0 + row * 232 + 4 * q] = xo;
  }
  __syncthreads();

  // ---- encoder ----
  layer_act<7, 6>(sU, XA0, 232, H1o, 104, ws, WS_E1, p.e_b1, 96, 1, lane, wv);
  __syncthreads();
  layer_act<3, 4>(sU, H1o, 104, H2o, 72, ws, WS_E2, p.e_b2, 64, 1, lane, wv);
  __syncthreads();
  layer_act<2, 2>(sU, H2o, 72, H3o, 40, ws, WS_E3, p.e_b3, 32, 1, lane, wv);
  __syncthreads();

  // ---- mean / logvar ----
  for (int t = wv; t < 2; t += 4) {
    int mt = t & 1;
    f32x4 acc = tile_acc<1>(sU + H3o, 40, ws + WS_EMV, mt, 0, lane);
    int col = lane & 15;
#pragma unroll
    for (int r = 0; r < 4; ++r) {
      int row = mt * 16 + ((lane >> 4) << 2) + r;
      if (col < 8) {
        float v = acc[r] + p.e_bm[col];
        sF[row * 9 + col] = v;
        __builtin_nontemporal_store(v, p.out + OFF_MEAN + (size_t)(rb0 + row) * 8 + col);
      } else {
        float v = acc[r] + p.e_bv[col - 8];
        __builtin_nontemporal_store(v, p.out + OFF_LOGV + (size_t)(rb0 + row) * 8 + (col - 8));
        sF[288 + row * 9 + (col - 8)] = __expf(0.5f * v);
      }
    }
  }
  __syncthreads();

  // ---- z draw helper ----
  auto do_z = [&](int dk) {
    int row = tid >> 3, jj = tid & 7;
    float eps = jax_normal(p.key[2 * dk], p.key[2 * dk + 1], (uint32_t)(rb0 + row) * 8u + jj);
    float zv = fmaf(eps, sF[288 + row * 9 + jj], sF[row * 9 + jj]);
    sU[ZBo + row * 40 + jj] = f2b(zv);
  };
  auto dec_hidden = [&]() {
    layer_act<1, 2>(sU, ZBo, 40, D1o, 40, ws, WS_D1, p.d_b1, 32, 1, lane, wv);
    __syncthreads();
    layer_act<1, 4>(sU, D1o, 40, D2o, 72, ws, WS_D2, p.d_b2, 64, 1, lane, wv);
    __syncthreads();
    layer_act<2, 6>(sU, D2o, 72, D3o, 104, ws, WS_D3, p.d_b3, 96, 1, lane, wv);
    __syncthreads();
  };

  // ---- draw 0: recon ----
  do_z(0);
  { int row = tid >> 3; for (int c = 8 + (tid & 7); c < 40; c += 8) sU[ZBo + row * 40 + c] = 0; }
  __syncthreads();
  dec_hidden();
  for (int t = wv; t < 26; t += 4) {
    int mt = t & 1, nt = t >> 1;
    f32x4 acc = tile_acc<3>(sU + D3o, 104, ws + WS_D4, mt, nt, lane);
    int col = nt * 16 + (lane & 15);
    if (col < 196) {
      float bv = p.d_b4[col];
#pragma unroll
      for (int r = 0; r < 4; ++r) {
        int row = mt * 16 + ((lane >> 4) << 2) + r;
        __builtin_nontemporal_store(sigm(acc[r] + bv),
            p.out + OFF_RECON + (size_t)(rb0 + row) * 196 + col);
      }
    }
  }
  do_z(1);
  __syncthreads();

  // ---- draws 1..3: layer losses ----
  dec_hidden();
  loss_tail<6>(sU, sF, ws, p.d_b4, H1o, 104, 1.0f / 96.0f, 0, lane, wv);
  do_z(2);
  __syncthreads();
  dec_hidden();
  loss_tail<4>(sU, sF, ws, p.d_b4, H2o, 72, 1.0f / 64.0f, 1, lane, wv);
  do_z(3);
  __syncthreads();
  dec_hidden();
  loss_tail<2>(sU, sF, ws, p.d_b4, H3o, 40, 1.0f / 32.0f, 2, lane, wv);
  __syncthreads();

  // ---- layer attention + weighted loss ----
  if (tid < 32) {
    int r = tid;
    float l0 = sF[608 + r], l1 = sF[640 + r], l2 = sF[672 + r];
    float lg[3];
#pragma unroll
    for (int i = 0; i < 3; ++i)
      lg[i] = p.la_b[i] + l0 * p.la_w[0 * 3 + i] + l1 * p.la_w[1 * 3 + i] + l2 * p.la_w[2 * 3 + i];
    float mx = fmaxf(lg[0], fmaxf(lg[1], lg[2]));
    float e0 = __expf(lg[0] - mx), e1 = __expf(lg[1] - mx), e2 = __expf(lg[2] - mx);
    float inv = 1.0f / (e0 + e1 + e2);
    float wll = (l0 * e0 + l1 * e1 + l2 * e2) * inv;
#pragma unroll
    for (int m = 1; m <= 16; m <<= 1) wll += __shfl_xor(wll, m, 64);
    if (tid == 0) atomicAdd(p.out + OFF_LOSS, wll * (1.0f / 262144.0f));
  }
}

// ------------------------------ host launcher ------------------------------
extern "C" void kernel_launch(void* const* d_in, const int* in_sizes, int n_in,
                              void* d_out, int out_size, void* d_ws, size_t ws_size,
                              hipStream_t stream)
{
  (void)in_sizes; (void)n_in; (void)ws_size; (void)out_size;
  Params p;
  p.x     = (const float*)d_in[0];
  p.fa_w1 = (const float*)d_in[1];  p.fa_b1 = (const float*)d_in[2];
  p.fa_w2 = (const float*)d_in[3];  p.fa_b2 = (const float*)d_in[4];
  p.e_w1  = (const float*)d_in[5];  p.e_b1  = (const float*)d_in[6];
  p.e_w2  = (const float*)d_in[7];  p.e_b2  = (const float*)d_in[8];
  p.e_w3  = (const float*)d_in[9];  p.e_b3  = (const float*)d_in[10];
  p.e_wm  = (const float*)d_in[11]; p.e_bm  = (const float*)d_in[12];
  p.e_wv  = (const float*)d_in[13]; p.e_bv  = (const float*)d_in[14];
  p.d_w1  = (const float*)d_in[15]; p.d_b1  = (const float*)d_in[16];
  p.d_w2  = (const float*)d_in[17]; p.d_b2  = (const float*)d_in[18];
  p.d_w3  = (const float*)d_in[19]; p.d_b3  = (const float*)d_in[20];
  p.d_w4  = (const float*)d_in[21]; p.d_b4  = (const float*)d_in[22];
  p.la_w  = (const float*)d_in[23]; p.la_b  = (const float*)d_in[24];
  p.out   = (float*)d_out;

  // jax.random.split(jax.random.key(42), 4), partitionable mode
  for (uint32_t j = 0; j < 4; ++j) {
    uint32_t o0, o1;
    tf2x32(0u, 42u, 0u, j, o0, o1);
    p.key[2 * j] = o0; p.key[2 * j + 1] = o1;
  }

  hipMemsetAsync((char*)d_out + OFF_LOSS * sizeof(float), 0, sizeof(float), stream);

  unsigned short* ws = (unsigned short*)d_ws;
  pack_w<<<(WS_TOT + 255) / 256, 256, 0, stream>>>(p, ws);
  vae_fused<<<262144 / 32, 256, 0, stream>>>(p, ws);
}

// Round 4
// 339.924 us; speedup vs baseline: 7.5917x; 1.2371x over previous
//
#include <hip/hip_runtime.h>
#include <cstdint>
#include <cstddef>

// ---------------------------------------------------------------------------
// AttentionVAE fused forward — bf16 MFMA, operand-swapped (C^T) version.
// One block = 32 rows, 256 threads = 4 waves.
// mfma(W_frag, act_frag): lane&15 = batch row, acc regs = 4 consecutive
// features -> vectorized epilogues (f32x4 bias, cvt_pk, ds_write_b64).
// Weights pre-packed to fragment order + padded f32 biases in d_ws.
// ---------------------------------------------------------------------------

typedef short short8 __attribute__((ext_vector_type(8)));
typedef float f32x4  __attribute__((ext_vector_type(4)));
typedef unsigned short u16x4 __attribute__((ext_vector_type(4)));
typedef uint32_t u32x2 __attribute__((ext_vector_type(2)));

static constexpr size_t OFF_RECON = 0;
static constexpr size_t OFF_MEAN  = (size_t)262144 * 196;
static constexpr size_t OFF_LOGV  = OFF_MEAN + (size_t)262144 * 8;
static constexpr size_t OFF_ATTN  = OFF_LOGV + (size_t)262144 * 8;
static constexpr size_t OFF_LOSS  = OFF_ATTN + (size_t)262144 * 196;

// ws fragment offsets (bf16 elements). elems = Kt*Nt*512 per layer.
static constexpr int WS_FA1 = 0;       // K196 N98  Kt7 Nt7
static constexpr int WS_FA2 = 25088;   // K98  N196 Kt4 Nt13
static constexpr int WS_E1  = 51712;   // K196 N96  Kt7 Nt6
static constexpr int WS_E2  = 73216;   // K96  N64  Kt3 Nt4
static constexpr int WS_E3  = 79360;   // K64  N32  Kt2 Nt2
static constexpr int WS_EMV = 81408;   // K32  N16  Kt1 Nt1 (mean|logvar)
static constexpr int WS_D1  = 81920;   // K8   N32  Kt1 Nt2
static constexpr int WS_D2  = 82944;   // K32  N64  Kt1 Nt4
static constexpr int WS_D3  = 84992;   // K64  N96  Kt2 Nt6
static constexpr int WS_D4  = 91136;   // K96  N196 Kt3 Nt13
static constexpr int WS_TOT = 111104;
// f32 bias region (floats, at (float*)(ws) + WS_TOT/2... we use ws as u16*,
// bias base = (const float*)(ws + WS_TOT)). Padded per-layer to mult of 16.
static constexpr int WB_FA1 = 0;    // 112
static constexpr int WB_FA2 = 112;  // 208
static constexpr int WB_E1  = 320;  // 96
static constexpr int WB_E2  = 416;  // 64
static constexpr int WB_E3  = 480;  // 32
static constexpr int WB_EMV = 512;  // 16
static constexpr int WB_D1  = 528;  // 32
static constexpr int WB_D2  = 560;  // 64
static constexpr int WB_D3  = 624;  // 96
static constexpr int WB_D4  = 720;  // 208
static constexpr int WB_TOT = 928;

// LDS layout (ushort units)
static constexpr int XA0 = 0;      // [32][232] x / x_attn
static constexpr int T0  = 7424;   // [32][136] fa hidden
static constexpr int R30 = 11776;  // TA [32][200] a-vals; later DEC2/DEC3
static constexpr int H1o = T0;     // [32][104]
static constexpr int H2o = 0;      // [32][72]
static constexpr int H3o = 2304;   // [32][40]
static constexpr int ZBo = 3584;   // [32][40]
static constexpr int D1o = 4864;   // [32][40]
static constexpr int D2o = R30;          // [32][72]
static constexpr int D3o = R30 + 2304;   // [32][104]
static constexpr int SU_TOT = 18176;
// sF: MEAN [32][9] @0, STD [32][9] @288, ATT[32] @576, LL[3][32] @608
static constexpr int SF_TOT = 704;

struct Params {
  const float* x;
  const float* fa_w1; const float* fa_b1; const float* fa_w2; const float* fa_b2;
  const float* e_w1;  const float* e_b1;  const float* e_w2;  const float* e_b2;
  const float* e_w3;  const float* e_b3;  const float* e_wm;  const float* e_bm;
  const float* e_wv;  const float* e_bv;
  const float* d_w1;  const float* d_b1;  const float* d_w2;  const float* d_b2;
  const float* d_w3;  const float* d_b3;  const float* d_w4;  const float* d_b4;
  const float* la_w;  const float* la_b;
  float* out;
  uint32_t key[8];
};

// --------------------------- Threefry-2x32 (JAX) ---------------------------
__host__ __device__ inline void tf2x32(uint32_t k0, uint32_t k1, uint32_t x0, uint32_t x1,
                                       uint32_t& o0, uint32_t& o1)
{
  uint32_t kx = k0 ^ k1 ^ 0x1BD11BDAu;
  uint32_t a = x0 + k0, b = x1 + k1;
#define TF_R(r) { a += b; b = (b << (r)) | (b >> (32 - (r))); b ^= a; }
  TF_R(13) TF_R(15) TF_R(26) TF_R(6)
  a += k1; b += kx + 1u;
  TF_R(17) TF_R(29) TF_R(16) TF_R(24)
  a += kx; b += k0 + 2u;
  TF_R(13) TF_R(15) TF_R(26) TF_R(6)
  a += k0; b += k1 + 3u;
  TF_R(17) TF_R(29) TF_R(16) TF_R(24)
  a += k1; b += kx + 4u;
  TF_R(13) TF_R(15) TF_R(26) TF_R(6)
  a += kx; b += k0 + 5u;
#undef TF_R
  o0 = a; o1 = b;
}

__device__ __forceinline__ float jax_normal(uint32_t k0, uint32_t k1, uint32_t idx)
{
  uint32_t o0, o1;
  tf2x32(k0, k1, 0u, idx, o0, o1);
  uint32_t bits = o0 ^ o1;
  float f = __uint_as_float((bits >> 9) | 0x3f800000u) - 1.0f;
  const float lo = -0.99999994f;
  float u = fmaf(f, 2.0f, lo);
  u = fmaxf(u, lo);
  float w = -log1pf(-u * u);
  float p;
  if (w < 5.0f) {
    w -= 2.5f;
    p = 2.81022636e-08f;
    p = fmaf(p, w, 3.43273939e-07f);
    p = fmaf(p, w, -3.5233877e-06f);
    p = fmaf(p, w, -4.39150654e-06f);
    p = fmaf(p, w, 0.00021858087f);
    p = fmaf(p, w, -0.00125372503f);
    p = fmaf(p, w, -0.00417768164f);
    p = fmaf(p, w, 0.246640727f);
    p = fmaf(p, w, 1.50140941f);
  } else {
    w = sqrtf(w) - 3.0f;
    p = -0.000200214257f;
    p = fmaf(p, w, 0.000100950558f);
    p = fmaf(p, w, 0.00134934322f);
    p = fmaf(p, w, -0.00367342844f);
    p = fmaf(p, w, 0.00573950773f);
    p = fmaf(p, w, -0.0076224613f);
    p = fmaf(p, w, 0.00943887047f);
    p = fmaf(p, w, 1.00167406f);
    p = fmaf(p, w, 2.83297682f);
  }
  return 1.41421356237f * (p * u);
}

// ------------------------------ helpers ------------------------------------
__host__ __device__ __forceinline__ unsigned short f2b(float f) {
  uint32_t u = __float_as_uint(f);
  uint32_t r = u + 0x7fffu + ((u >> 16) & 1u);   // RNE
  return (unsigned short)(r >> 16);
}
__device__ __forceinline__ float b2f(unsigned short h) {
  return __uint_as_float(((uint32_t)h) << 16);
}
__device__ __forceinline__ uint32_t cvt_pk(float lo, float hi) {
  uint32_t r;
  asm("v_cvt_pk_bf16_f32 %0, %1, %2" : "=v"(r) : "v"(lo), "v"(hi));
  return r;
}
__device__ __forceinline__ float rcpf(float x) { return __builtin_amdgcn_rcpf(x); }
__device__ __forceinline__ float sigm(float x) { return rcpf(1.0f + __expf(-x)); }
__device__ __forceinline__ float tanh_fast(float x) {
  float xc = fminf(fmaxf(x, -8.0f), 8.0f);
  float t = __expf(2.0f * xc);
  return (t - 1.0f) * rcpf(t + 1.0f);
}

// ------------------------------ weight packer ------------------------------
__global__ void pack_w(Params p, unsigned short* ws)
{
  int e = blockIdx.x * 256 + threadIdx.x;
  if (e < WS_TOT) {
    int base, Kt, K, N, special = 0; const float* src = nullptr;
    if (e < WS_FA2)      { base = WS_FA1; Kt = 7; K = 196; N = 98;  src = p.fa_w1; }
    else if (e < WS_E1)  { base = WS_FA2; Kt = 4; K = 98;  N = 196; src = p.fa_w2; }
    else if (e < WS_E2)  { base = WS_E1;  Kt = 7; K = 196; N = 96;  src = p.e_w1; }
    else if (e < WS_E3)  { base = WS_E2;  Kt = 3; K = 96;  N = 64;  src = p.e_w2; }
    else if (e < WS_EMV) { base = WS_E3;  Kt = 2; K = 64;  N = 32;  src = p.e_w3; }
    else if (e < WS_D1)  { base = WS_EMV; Kt = 1; K = 32;  N = 16;  special = 1; }
    else if (e < WS_D2)  { base = WS_D1;  Kt = 1; K = 8;   N = 32;  src = p.d_w1; }
    else if (e < WS_D3)  { base = WS_D2;  Kt = 1; K = 32;  N = 64;  src = p.d_w2; }
    else if (e < WS_D4)  { base = WS_D3;  Kt = 2; K = 64;  N = 96;  src = p.d_w3; }
    else                 { base = WS_D4;  Kt = 3; K = 96;  N = 196; src = p.d_w4; }
    int local = e - base;
    int j = local & 7;
    int lane = (local >> 3) & 63;
    int t = local >> 9;
    int kt = t % Kt, nt = t / Kt;
    int k = kt * 32 + ((lane >> 4) << 3) + j;
    int n = (nt << 4) + (lane & 15);
    float v = 0.f;
    if (k < K && n < N) {
      if (special) v = (n < 8) ? p.e_wm[k * 8 + n] : p.e_wv[k * 8 + (n - 8)];
      else v = src[k * N + n];
    }
    ws[e] = f2b(v);
    return;
  }
  int b = e - WS_TOT;
  if (b >= WB_TOT) return;
  float v = 0.f;
  if      (b < WB_FA2) { int i = b - WB_FA1; if (i < 98)  v = p.fa_b1[i]; }
  else if (b < WB_E1)  { int i = b - WB_FA2; if (i < 196) v = p.fa_b2[i]; }
  else if (b < WB_E2)  { int i = b - WB_E1;  if (i < 96)  v = p.e_b1[i]; }
  else if (b < WB_E3)  { int i = b - WB_E2;  if (i < 64)  v = p.e_b2[i]; }
  else if (b < WB_EMV) { int i = b - WB_E3;  if (i < 32)  v = p.e_b3[i]; }
  else if (b < WB_D1)  { int i = b - WB_EMV; v = (i < 8) ? p.e_bm[i] : p.e_bv[i - 8]; }
  else if (b < WB_D2)  { int i = b - WB_D1;  if (i < 32)  v = p.d_b1[i]; }
  else if (b < WB_D3)  { int i = b - WB_D2;  if (i < 64)  v = p.d_b2[i]; }
  else if (b < WB_D4)  { int i = b - WB_D3;  if (i < 96)  v = p.d_b3[i]; }
  else                 { int i = b - WB_D4;  if (i < 196) v = p.d_b4[i]; }
  ((float*)(ws + WS_TOT))[b] = v;
}

// ------------------------------ MFMA tile (swapped) ------------------------
// W as A-operand (lane&15 = feature n, k=(lane>>4)*8+j) — packed order.
// act as B-operand (lane&15 = batch row m, k consecutive) — LDS row read.
// C: col = lane&15 = batch row m; row = (lane>>4)*4 + r = feature.
template<int Kt>
__device__ __forceinline__ f32x4 tile_acc(const unsigned short* A, int sA,
                                          const unsigned short* W,
                                          int bt, int ft, int lane)
{
  f32x4 acc = {0.f, 0.f, 0.f, 0.f};
  const unsigned short* ar = A + (bt * 16 + (lane & 15)) * sA + ((lane >> 4) << 3);
  const unsigned short* wp = W + ((ft * Kt) * 64 + lane) * 8;
#pragma unroll
  for (int kt = 0; kt < Kt; ++kt) {
    short8 av = *(const short8*)(ar + kt * 32);
    short8 wv8 = *(const short8*)(wp + kt * 512);
    acc = __builtin_amdgcn_mfma_f32_16x16x32_bf16(wv8, av, acc, 0, 0, 0);
  }
  return acc;
}

// generic GEMM + act + bf16 LDS store (b64). act: 0 tanh, 1 lrelu
template<int Kt, int Nt>
__device__ __forceinline__ void layer_act(unsigned short* sU, int aOff, int sA,
                                          int dOff, int sD,
                                          const unsigned short* ws, int wsOff,
                                          const float* biasF, int act,
                                          int lane, int wv)
{
  for (int t = wv; t < 2 * Nt; t += 4) {
    int bt = t & 1, ft = t >> 1;
    f32x4 acc = tile_acc<Kt>(sU + aOff, sA, ws + wsOff, bt, ft, lane);
    int m = bt * 16 + (lane & 15);
    int fb = ft * 16 + ((lane >> 4) << 2);
    f32x4 bv = *(const f32x4*)(biasF + fb);
    float v[4];
#pragma unroll
    for (int r = 0; r < 4; ++r) {
      float y = acc[r] + bv[r];
      v[r] = (act == 0) ? tanh_fast(y) : (y > 0.f ? y : 0.1f * y);
    }
    u32x2 pk = { cvt_pk(v[0], v[1]), cvt_pk(v[2], v[3]) };
    *(u32x2*)&sU[dOff + m * sD + fb] = pk;
  }
}

// D4 partial (loss) tail — exact feature tiles
template<int NtL>
__device__ __forceinline__ void loss_tail(unsigned short* sU, float* sF,
                                          const unsigned short* ws,
                                          const float* biasD4,
                                          int hOff, int sH, float invD, int li,
                                          int lane, int wv)
{
  for (int t = wv; t < 2 * NtL; t += 4) {
    int bt = t & 1, ft = t >> 1;
    f32x4 acc = tile_acc<3>(sU + D3o, 104, ws + WS_D4, bt, ft, lane);
    int m = bt * 16 + (lane & 15);
    int fb = ft * 16 + ((lane >> 4) << 2);
    f32x4 bv = *(const f32x4*)(biasD4 + fb);
    u16x4 hh = *(const u16x4*)&sU[hOff + m * sH + fb];
    float s = 0.f;
#pragma unroll
    for (int r = 0; r < 4; ++r) {
      float lr = sigm(acc[r] + bv[r]);
      float d = b2f(hh[r]) - lr;
      s = fmaf(d, d, s);
    }
    s += __shfl_xor(s, 16, 64);
    s += __shfl_xor(s, 32, 64);
    if (lane < 16) atomicAdd(&sF[608 + li * 32 + m], s * invD);
  }
}

// ------------------------------- the kernel --------------------------------
__launch_bounds__(256, 4)
__global__ void vae_fused(Params p, const unsigned short* ws)
{
  __shared__ unsigned short sU[SU_TOT];
  __shared__ float sF[SF_TOT];

  const int tid = threadIdx.x;
  const int lane = tid & 63;
  const int wv = tid >> 6;
  const int rb0 = blockIdx.x * 32;
  const float* wb = (const float*)(ws + WS_TOT);

  // ---- init: zero accumulators; load x (float4 -> bf16); zero pads ----
  if (tid < 128) sF[576 + tid] = 0.f;
  for (int idx = tid; idx < 1568; idx += 256) {           // 32 rows * 49 quads
    int row = idx / 49, q = idx - row * 49;
    f32x4 xv = *(const f32x4*)(p.x + (size_t)(rb0 + row) * 196 + 4 * q);
    u32x2 h = { cvt_pk(xv[0], xv[1]), cvt_pk(xv[2], xv[3]) };
    *(u32x2*)&sU[XA0 + row * 232 + 4 * q] = h;
  }
  { int row = tid >> 3; for (int c = 196 + (tid & 7); c < 232; c += 8) sU[XA0 + row * 232 + c] = 0; }
  __syncthreads();

  // ---- FA1: T = tanh(x @ fa_w1 + b)  [K196 N98] (pads write 0) ----
  layer_act<7, 7>(sU, XA0, 232, T0, 136, ws, WS_FA1, wb + WB_FA1, 0, lane, wv);
  { int row = tid >> 3; for (int c = 112 + (tid & 7); c < 136; c += 8) sU[T0 + row * 136 + c] = 0; }
  __syncthreads();

  // ---- FA2: a = sigmoid(T @ fa_w2 + b) -> TA, row sums -> sF[576+] ----
  for (int t = wv; t < 26; t += 4) {
    int bt = t & 1, ft = t >> 1;
    f32x4 acc = tile_acc<4>(sU + T0, 136, ws + WS_FA2, bt, ft, lane);
    int m = bt * 16 + (lane & 15);
    int fb = ft * 16 + ((lane >> 4) << 2);
    bool vld = fb < 196;
    f32x4 bv = *(const f32x4*)(wb + WB_FA2 + fb);
    float a[4];
    float s = 0.f;
#pragma unroll
    for (int r = 0; r < 4; ++r) {
      a[r] = sigm(acc[r] + bv[r]);
      s += a[r];
    }
    if (vld) {
      u32x2 pk = { cvt_pk(a[0], a[1]), cvt_pk(a[2], a[3]) };
      *(u32x2*)&sU[R30 + m * 200 + fb] = pk;
    } else s = 0.f;
    s += __shfl_xor(s, 16, 64);
    s += __shfl_xor(s, 32, 64);
    if (lane < 16) atomicAdd(&sF[576 + m], s);
  }
  __syncthreads();

  // ---- attention apply: attn_out = a*inv, XA *= a*inv ----
  for (int idx = tid; idx < 1568; idx += 256) {
    int row = idx / 49, q = idx - row * 49;
    float inv = rcpf(sF[576 + row] * (1.0f / 196.0f) + 1e-8f);
    u16x4 ah = *(const u16x4*)&sU[R30 + row * 200 + 4 * q];
    u16x4 xh = *(const u16x4*)&sU[XA0 + row * 232 + 4 * q];
    f32x4 aw;
    float xo[4];
#pragma unroll
    for (int i = 0; i < 4; ++i) {
      aw[i] = b2f(ah[i]) * inv;
      xo[i] = b2f(xh[i]) * aw[i];
    }
    __builtin_nontemporal_store(aw, (f32x4*)(p.out + OFF_ATTN + (size_t)(rb0 + row) * 196 + 4 * q));
    u32x2 pk = { cvt_pk(xo[0], xo[1]), cvt_pk(xo[2], xo[3]) };
    *(u32x2*)&sU[XA0 + row * 232 + 4 * q] = pk;
  }
  __syncthreads();

  // ---- encoder (all dims exact multiples -> no pad zeroing) ----
  layer_act<7, 6>(sU, XA0, 232, H1o, 104, ws, WS_E1, wb + WB_E1, 1, lane, wv);
  __syncthreads();
  layer_act<3, 4>(sU, H1o, 104, H2o, 72, ws, WS_E2, wb + WB_E2, 1, lane, wv);
  __syncthreads();
  layer_act<2, 2>(sU, H2o, 72, H3o, 40, ws, WS_E3, wb + WB_E3, 1, lane, wv);
  __syncthreads();

  // ---- mean / logvar (feats 0-7 mean, 8-15 logvar; per lane-group) ----
  for (int t = wv; t < 2; t += 4) {
    int bt = t & 1;
    f32x4 acc = tile_acc<1>(sU + H3o, 40, ws + WS_EMV, bt, 0, lane);
    int m = bt * 16 + (lane & 15);
    int fb = (lane >> 4) << 2;
    f32x4 bv = *(const f32x4*)(wb + WB_EMV + fb);
    f32x4 v;
#pragma unroll
    for (int r = 0; r < 4; ++r) v[r] = acc[r] + bv[r];
    if (fb < 8) {
#pragma unroll
      for (int r = 0; r < 4; ++r) sF[m * 9 + fb + r] = v[r];
      __builtin_nontemporal_store(v, (f32x4*)(p.out + OFF_MEAN + (size_t)(rb0 + m) * 8 + fb));
    } else {
      __builtin_nontemporal_store(v, (f32x4*)(p.out + OFF_LOGV + (size_t)(rb0 + m) * 8 + (fb - 8)));
#pragma unroll
      for (int r = 0; r < 4; ++r) sF[288 + m * 9 + (fb - 8) + r] = __expf(0.5f * v[r]);
    }
  }
  __syncthreads();

  // ---- z draw helper ----
  auto do_z = [&](int dk) {
    int row = tid >> 3, jj = tid & 7;
    float eps = jax_normal(p.key[2 * dk], p.key[2 * dk + 1], (uint32_t)(rb0 + row) * 8u + jj);
    float zv = fmaf(eps, sF[288 + row * 9 + jj], sF[row * 9 + jj]);
    sU[ZBo + row * 40 + jj] = f2b(zv);
  };
  auto dec_hidden = [&]() {
    layer_act<1, 2>(sU, ZBo, 40, D1o, 40, ws, WS_D1, wb + WB_D1, 1, lane, wv);
    __syncthreads();
    layer_act<1, 4>(sU, D1o, 40, D2o, 72, ws, WS_D2, wb + WB_D2, 1, lane, wv);
    __syncthreads();
    layer_act<2, 6>(sU, D2o, 72, D3o, 104, ws, WS_D3, wb + WB_D3, 1, lane, wv);
    __syncthreads();
  };

  // ---- draw 0: recon ----
  do_z(0);
  { int row = tid >> 3; for (int c = 8 + (tid & 7); c < 40; c += 8) sU[ZBo + row * 40 + c] = 0; }
  __syncthreads();
  dec_hidden();
  for (int t = wv; t < 26; t += 4) {
    int bt = t & 1, ft = t >> 1;
    f32x4 acc = tile_acc<3>(sU + D3o, 104, ws + WS_D4, bt, ft, lane);
    int m = bt * 16 + (lane & 15);
    int fb = ft * 16 + ((lane >> 4) << 2);
    if (fb < 196) {
      f32x4 bv = *(const f32x4*)(wb + WB_D4 + fb);
      f32x4 v;
#pragma unroll
      for (int r = 0; r < 4; ++r) v[r] = sigm(acc[r] + bv[r]);
      __builtin_nontemporal_store(v, (f32x4*)(p.out + OFF_RECON + (size_t)(rb0 + m) * 196 + fb));
    }
  }
  do_z(1);
  __syncthreads();

  // ---- draws 1..3: layer losses ----
  dec_hidden();
  loss_tail<6>(sU, sF, ws, wb + WB_D4, H1o, 104, 1.0f / 96.0f, 0, lane, wv);
  do_z(2);
  __syncthreads();
  dec_hidden();
  loss_tail<4>(sU, sF, ws, wb + WB_D4, H2o, 72, 1.0f / 64.0f, 1, lane, wv);
  do_z(3);
  __syncthreads();
  dec_hidden();
  loss_tail<2>(sU, sF, ws, wb + WB_D4, H3o, 40, 1.0f / 32.0f, 2, lane, wv);
  __syncthreads();

  // ---- layer attention + weighted loss ----
  if (tid < 32) {
    int r = tid;
    float l0 = sF[608 + r], l1 = sF[640 + r], l2 = sF[672 + r];
    float lg[3];
#pragma unroll
    for (int i = 0; i < 3; ++i)
      lg[i] = p.la_b[i] + l0 * p.la_w[0 * 3 + i] + l1 * p.la_w[1 * 3 + i] + l2 * p.la_w[2 * 3 + i];
    float mx = fmaxf(lg[0], fmaxf(lg[1], lg[2]));
    float e0 = __expf(lg[0] - mx), e1 = __expf(lg[1] - mx), e2 = __expf(lg[2] - mx);
    float inv = rcpf(e0 + e1 + e2);
    float wll = (l0 * e0 + l1 * e1 + l2 * e2) * inv;
#pragma unroll
    for (int m = 1; m <= 16; m <<= 1) wll += __shfl_xor(wll, m, 64);
    if (tid == 0) atomicAdd(p.out + OFF_LOSS, wll * (1.0f / 262144.0f));
  }
}

// ------------------------------ host launcher ------------------------------
extern "C" void kernel_launch(void* const* d_in, const int* in_sizes, int n_in,
                              void* d_out, int out_size, void* d_ws, size_t ws_size,
                              hipStream_t stream)
{
  (void)in_sizes; (void)n_in; (void)ws_size; (void)out_size;
  Params p;
  p.x     = (const float*)d_in[0];
  p.fa_w1 = (const float*)d_in[1];  p.fa_b1 = (const float*)d_in[2];
  p.fa_w2 = (const float*)d_in[3];  p.fa_b2 = (const float*)d_in[4];
  p.e_w1  = (const float*)d_in[5];  p.e_b1  = (const float*)d_in[6];
  p.e_w2  = (const float*)d_in[7];  p.e_b2  = (const float*)d_in[8];
  p.e_w3  = (const float*)d_in[9];  p.e_b3  = (const float*)d_in[10];
  p.e_wm  = (const float*)d_in[11]; p.e_bm  = (const float*)d_in[12];
  p.e_wv  = (const float*)d_in[13]; p.e_bv  = (const float*)d_in[14];
  p.d_w1  = (const float*)d_in[15]; p.d_b1  = (const float*)d_in[16];
  p.d_w2  = (const float*)d_in[17]; p.d_b2  = (const float*)d_in[18];
  p.d_w3  = (const float*)d_in[19]; p.d_b3  = (const float*)d_in[20];
  p.d_w4  = (const float*)d_in[21]; p.d_b4  = (const float*)d_in[22];
  p.la_w  = (const float*)d_in[23]; p.la_b  = (const float*)d_in[24];
  p.out   = (float*)d_out;

  for (uint32_t j = 0; j < 4; ++j) {
    uint32_t o0, o1;
    tf2x32(0u, 42u, 0u, j, o0, o1);
    p.key[2 * j] = o0; p.key[2 * j + 1] = o1;
  }

  hipMemsetAsync((char*)d_out + OFF_LOSS * sizeof(float), 0, sizeof(float), stream);

  unsigned short* ws = (unsigned short*)d_ws;
  pack_w<<<(WS_TOT + WB_TOT + 255) / 256, 256, 0, stream>>>(p, ws);
  vae_fused<<<262144 / 32, 256, 0, stream>>>(p, ws);
}